// Round 1
// baseline (107.577 us; speedup 1.0000x reference)
//
#include <hip/hip_runtime.h>

#define BIGF 1.0e6f

static constexpr int B = 4, C = 3, H = 256, W = 256;
static constexpr int SLICES = B * C;        // 12
static constexpr int ROWS = SLICES * H;     // 3072
static constexpr int HW = H * W;            // 65536
static constexpr int TOTAL = SLICES * HW;   // 786432
static constexpr int COLS = 16;             // columns per block in col pass

__global__ void init_smax_kernel(unsigned* smax) {
    int t = threadIdx.x;
    if (t < SLICES) smax[t] = 0u;
}

// One thread per row: exact forward/backward 1D scan (same float ops as the
// reference scan -> bit-identical; all values are exact small ints or BIG).
__global__ void row_pass_kernel(const float* __restrict__ in, float* __restrict__ g2) {
    int r = blockIdx.x * blockDim.x + threadIdx.x;
    if (r >= ROWS) return;
    const float* row = in + (size_t)r * W;
    float* out = g2 + (size_t)r * W;
    float carry = BIGF;
    #pragma unroll 4
    for (int j = 0; j < W; ++j) {
        float f0 = (row[j] == 0.0f) ? 0.0f : BIGF;
        carry = fminf(f0, carry + 1.0f);
        out[j] = carry;                 // fwd pass result
    }
    carry = BIGF;
    #pragma unroll 4
    for (int j = W - 1; j >= 0; --j) {
        float b = fminf(out[j], carry + 1.0f);   // backward pass (same thread,
        carry = b;                               // reads its own writes)
        out[j] = b * b;                          // store g^2
    }
}

// Per (slice, 16-column tile): brute-force exact min-plus over k (matches the
// reference's full min over the H axis), then sqrt, store dt, per-slice max.
__launch_bounds__(256)
__global__ void col_pass_kernel(const float* __restrict__ g2, float* __restrict__ dt,
                                unsigned* __restrict__ smax) {
    __shared__ float tile[H][COLS];     // 16 KB
    int slice = blockIdx.y;
    int j0 = blockIdx.x * COLS;
    const float* g2s = g2 + (size_t)slice * HW;
    for (int e = threadIdx.x; e < H * COLS; e += 256) {
        int k = e >> 4, jl = e & (COLS - 1);
        tile[k][jl] = g2s[(size_t)k * W + j0 + jl];
    }
    __syncthreads();

    int jl = threadIdx.x & (COLS - 1);
    int ig = threadIdx.x >> 4;          // 16 groups of output rows
    int ibase = ig * 16;                // this thread: i in [ibase, ibase+16)
    float m[16];
    #pragma unroll
    for (int t = 0; t < 16; ++t) m[t] = 3.0e38f;

    for (int k = 0; k < H; ++k) {
        float gv = tile[k][jl];         // reused for 16 outputs
        float dbase = (float)(ibase - k);
        #pragma unroll
        for (int t = 0; t < 16; ++t) {
            float d = dbase + (float)t;            // exact int in f32
            m[t] = fminf(m[t], fmaf(d, d, gv));    // single-rounded, = ref add
        }
    }

    float* dts = dt + (size_t)slice * HW;
    float lmax = 0.0f;
    #pragma unroll
    for (int t = 0; t < 16; ++t) {
        float v = sqrtf(m[t]);
        dts[(size_t)(ibase + t) * W + j0 + jl] = v;
        lmax = fmaxf(lmax, v);
    }
    #pragma unroll
    for (int off = 32; off; off >>= 1) lmax = fmaxf(lmax, __shfl_down(lmax, off));
    if ((threadIdx.x & 63) == 0) atomicMax(&smax[slice], __float_as_uint(lmax));
}

// In-place: out = (dt / max) * w[c]   (same op order as reference)
__global__ void norm_kernel(float* __restrict__ out, const unsigned* __restrict__ smax,
                            const float* __restrict__ w) {
    int idx = blockIdx.x * blockDim.x + threadIdx.x;   // float4 index
    if (idx >= TOTAL / 4) return;
    int slice = idx >> 14;              // (idx*4) / 65536
    int c = slice % C;
    float mx = __uint_as_float(smax[slice]);
    float den = mx > 0.0f ? mx : 1.0f;
    float wc = w[c];
    float4 v = ((float4*)out)[idx];
    v.x = (v.x / den) * wc;
    v.y = (v.y / den) * wc;
    v.z = (v.z / den) * wc;
    v.w = (v.w / den) * wc;
    ((float4*)out)[idx] = v;
}

extern "C" void kernel_launch(void* const* d_in, const int* in_sizes, int n_in,
                              void* d_out, int out_size, void* d_ws, size_t ws_size,
                              hipStream_t stream) {
    const float* in = (const float*)d_in[0];
    const float* w  = (const float*)d_in[1];
    float* out = (float*)d_out;
    float* g2 = (float*)d_ws;
    unsigned* smax = (unsigned*)((char*)d_ws + (size_t)TOTAL * sizeof(float));

    init_smax_kernel<<<1, 64, 0, stream>>>(smax);
    row_pass_kernel<<<(ROWS + 255) / 256, 256, 0, stream>>>(in, g2);
    col_pass_kernel<<<dim3(W / COLS, SLICES), 256, 0, stream>>>(g2, out, smax);
    norm_kernel<<<(TOTAL / 4 + 255) / 256, 256, 0, stream>>>(out, smax, w);
}

// Round 2
// 57.837 us; speedup vs baseline: 1.8600x; 1.8600x over previous
//
#include <hip/hip_runtime.h>

#define BIGF 1.0e6f

static constexpr int B = 4, C = 3, H = 256, W = 256;
static constexpr int SLICES = B * C;        // 12
static constexpr int ROWS = SLICES * H;     // 3072
static constexpr int HW = H * W;            // 65536
static constexpr int TOTAL = SLICES * HW;   // 786432
static constexpr int COLS = 16;             // columns per block in col pass
static constexpr int ROWQ = 64;             // output rows per block in col pass

// ---------------------------------------------------------------------------
// Row pass: exact 1D distance along W, one WAVE per row (4 px/lane).
// d[j] = min(j - lastzero<=j, nextzero>=j - j, BIG)  ==  reference two-scan.
// All quantities exact ints; final float square matches reference rounding.
// Also zero-initializes the per-slice max slots (ws is poisoned each run).
// ---------------------------------------------------------------------------
__global__ void row_pass_kernel(const float* __restrict__ in, float* __restrict__ g2,
                                unsigned* __restrict__ smax) {
    if (blockIdx.x == 0 && threadIdx.x < SLICES) smax[threadIdx.x] = 0u;

    int wid = (blockIdx.x * blockDim.x + threadIdx.x) >> 6;   // global wave = row
    int lane = threadIdx.x & 63;
    if (wid >= ROWS) return;

    const float4 v = ((const float4*)(in + (size_t)wid * W))[lane];
    int j0 = lane * 4;
    const int NEG = -(1 << 29), POS = (1 << 29);

    bool z0 = (v.x == 0.0f), z1 = (v.y == 0.0f), z2 = (v.z == 0.0f), z3 = (v.w == 0.0f);
    int lz = NEG;                       // last (max) zero index in this lane
    if (z0) lz = j0;
    if (z1) lz = j0 + 1;
    if (z2) lz = j0 + 2;
    if (z3) lz = j0 + 3;
    int nz = POS;                       // first (min) zero index in this lane
    if (z3) nz = j0 + 3;
    if (z2) nz = j0 + 2;
    if (z1) nz = j0 + 1;
    if (z0) nz = j0;

    // inclusive prefix-max of lz across lanes, then shift to exclusive
    int plz = lz;
    #pragma unroll
    for (int off = 1; off < 64; off <<= 1) {
        int o = __shfl_up(plz, off);
        if (lane >= off) plz = max(plz, o);
    }
    int ex_lz = __shfl_up(plz, 1);
    if (lane == 0) ex_lz = NEG;

    // inclusive suffix-min of nz across lanes, then shift to exclusive
    int pnz = nz;
    #pragma unroll
    for (int off = 1; off < 64; off <<= 1) {
        int o = __shfl_down(pnz, off);
        if (lane + off < 64) pnz = min(pnz, o);
    }
    int ex_nz = __shfl_down(pnz, 1);
    if (lane == 63) ex_nz = POS;

    // per-pixel distances
    int lzr = ex_lz;
    int dl0, dl1, dl2, dl3;
    if (z0) lzr = j0;     dl0 = j0 - lzr;
    if (z1) lzr = j0 + 1; dl1 = j0 + 1 - lzr;
    if (z2) lzr = j0 + 2; dl2 = j0 + 2 - lzr;
    if (z3) lzr = j0 + 3; dl3 = j0 + 3 - lzr;

    int nzr = ex_nz;
    int dr0, dr1, dr2, dr3;
    if (z3) nzr = j0 + 3; dr3 = nzr - (j0 + 3);
    if (z2) nzr = j0 + 2; dr2 = nzr - (j0 + 2);
    if (z1) nzr = j0 + 1; dr1 = nzr - (j0 + 1);
    if (z0) nzr = j0;     dr0 = nzr - j0;

    float d0 = fminf((float)min(dl0, dr0), BIGF);
    float d1 = fminf((float)min(dl1, dr1), BIGF);
    float d2 = fminf((float)min(dl2, dr2), BIGF);
    float d3 = fminf((float)min(dl3, dr3), BIGF);

    float4 o;
    o.x = d0 * d0; o.y = d1 * d1; o.z = d2 * d2; o.w = d3 * d3;
    ((float4*)(g2 + (size_t)wid * W))[lane] = o;
}

// ---------------------------------------------------------------------------
// Column pass: per (slice, 64-row quad, 16-col tile). Brute-force exact
// min-plus over all k (identical op order to reference), sqrt, per-slice max.
// ---------------------------------------------------------------------------
__launch_bounds__(256)
__global__ void col_pass_kernel(const float* __restrict__ g2, float* __restrict__ dt,
                                unsigned* __restrict__ smax) {
    __shared__ float tile[H][COLS];     // 16 KB
    int slice = blockIdx.z;
    int i0 = blockIdx.y * ROWQ;
    int j0 = blockIdx.x * COLS;
    const float* g2s = g2 + (size_t)slice * HW;

    // stage the full column strip [256 k][16 cols] via float4
    for (int e = threadIdx.x; e < H * COLS / 4; e += 256) {
        int k = e >> 2, q = e & 3;
        *(float4*)&tile[k][q * 4] =
            *(const float4*)(g2s + (size_t)k * W + j0 + q * 4);
    }
    __syncthreads();

    int jl = threadIdx.x & (COLS - 1);
    int ig = threadIdx.x >> 4;          // 16 groups
    int ibase = i0 + ig * 4;            // 4 output rows per thread
    float m0 = 3.0e38f, m1 = 3.0e38f, m2 = 3.0e38f, m3 = 3.0e38f;

    #pragma unroll 4
    for (int k = 0; k < H; ++k) {
        float gv = tile[k][jl];
        float d = (float)(ibase - k);
        m0 = fminf(m0, fmaf(d, d, gv)); d += 1.0f;
        m1 = fminf(m1, fmaf(d, d, gv)); d += 1.0f;
        m2 = fminf(m2, fmaf(d, d, gv)); d += 1.0f;
        m3 = fminf(m3, fmaf(d, d, gv));
    }

    float* dts = dt + (size_t)slice * HW + (size_t)ibase * W + j0 + jl;
    float v0 = sqrtf(m0), v1 = sqrtf(m1), v2 = sqrtf(m2), v3 = sqrtf(m3);
    dts[0] = v0; dts[W] = v1; dts[2 * W] = v2; dts[3 * W] = v3;

    float lmax = fmaxf(fmaxf(v0, v1), fmaxf(v2, v3));
    #pragma unroll
    for (int off = 32; off; off >>= 1) lmax = fmaxf(lmax, __shfl_down(lmax, off));
    if ((threadIdx.x & 63) == 0) atomicMax(&smax[slice], __float_as_uint(lmax));
}

// In-place: out = (dt / max) * w[c]   (same op order as reference)
__global__ void norm_kernel(float* __restrict__ out, const unsigned* __restrict__ smax,
                            const float* __restrict__ w) {
    int idx = blockIdx.x * blockDim.x + threadIdx.x;   // float4 index
    if (idx >= TOTAL / 4) return;
    int slice = idx >> 14;              // (idx*4) / 65536
    int c = slice % C;
    float mx = __uint_as_float(smax[slice]);
    float den = mx > 0.0f ? mx : 1.0f;
    float wc = w[c];
    float4 v = ((float4*)out)[idx];
    v.x = (v.x / den) * wc;
    v.y = (v.y / den) * wc;
    v.z = (v.z / den) * wc;
    v.w = (v.w / den) * wc;
    ((float4*)out)[idx] = v;
}

extern "C" void kernel_launch(void* const* d_in, const int* in_sizes, int n_in,
                              void* d_out, int out_size, void* d_ws, size_t ws_size,
                              hipStream_t stream) {
    const float* in = (const float*)d_in[0];
    const float* w  = (const float*)d_in[1];
    float* out = (float*)d_out;
    float* g2 = (float*)d_ws;
    unsigned* smax = (unsigned*)((char*)d_ws + (size_t)TOTAL * sizeof(float));

    row_pass_kernel<<<ROWS * 64 / 256, 256, 0, stream>>>(in, g2, smax);
    col_pass_kernel<<<dim3(W / COLS, H / ROWQ, SLICES), 256, 0, stream>>>(g2, out, smax);
    norm_kernel<<<(TOTAL / 4 + 255) / 256, 256, 0, stream>>>(out, smax, w);
}

// Round 3
// 51.946 us; speedup vs baseline: 2.0709x; 1.1134x over previous
//
#include <hip/hip_runtime.h>

#define BIGF 1.0e6f

static constexpr int B = 4, C = 3, H = 256, W = 256;
static constexpr int SLICES = B * C;        // 12
static constexpr int ROWS = SLICES * H;     // 3072
static constexpr int HW = H * W;            // 65536
static constexpr int TOTAL = SLICES * HW;   // 786432
static constexpr int COLS = 16;             // columns per block in col pass
static constexpr int ROWQ = 64;             // output rows per block in col pass
static constexpr int PADH = H + 4;          // 260: 16B-aligned rows, banks ~2-way

// ---------------------------------------------------------------------------
// Row pass: exact 1D distance along W, one WAVE per row (4 px/lane).
// d[j] = min(j - lastzero<=j, nextzero>=j - j, BIG)  ==  reference two-scan.
// Also zero-initializes the per-slice max slots (ws is poisoned each run).
// ---------------------------------------------------------------------------
__global__ void row_pass_kernel(const float* __restrict__ in, float* __restrict__ g2,
                                unsigned* __restrict__ smax) {
    if (blockIdx.x == 0 && threadIdx.x < SLICES) smax[threadIdx.x] = 0u;

    int wid = (blockIdx.x * blockDim.x + threadIdx.x) >> 6;   // global wave = row
    int lane = threadIdx.x & 63;
    if (wid >= ROWS) return;

    const float4 v = ((const float4*)(in + (size_t)wid * W))[lane];
    int j0 = lane * 4;
    const int NEG = -(1 << 29), POS = (1 << 29);

    bool z0 = (v.x == 0.0f), z1 = (v.y == 0.0f), z2 = (v.z == 0.0f), z3 = (v.w == 0.0f);
    int lz = NEG;
    if (z0) lz = j0;
    if (z1) lz = j0 + 1;
    if (z2) lz = j0 + 2;
    if (z3) lz = j0 + 3;
    int nz = POS;
    if (z3) nz = j0 + 3;
    if (z2) nz = j0 + 2;
    if (z1) nz = j0 + 1;
    if (z0) nz = j0;

    int plz = lz;
    #pragma unroll
    for (int off = 1; off < 64; off <<= 1) {
        int o = __shfl_up(plz, off);
        if (lane >= off) plz = max(plz, o);
    }
    int ex_lz = __shfl_up(plz, 1);
    if (lane == 0) ex_lz = NEG;

    int pnz = nz;
    #pragma unroll
    for (int off = 1; off < 64; off <<= 1) {
        int o = __shfl_down(pnz, off);
        if (lane + off < 64) pnz = min(pnz, o);
    }
    int ex_nz = __shfl_down(pnz, 1);
    if (lane == 63) ex_nz = POS;

    int lzr = ex_lz;
    int dl0, dl1, dl2, dl3;
    if (z0) lzr = j0;     dl0 = j0 - lzr;
    if (z1) lzr = j0 + 1; dl1 = j0 + 1 - lzr;
    if (z2) lzr = j0 + 2; dl2 = j0 + 2 - lzr;
    if (z3) lzr = j0 + 3; dl3 = j0 + 3 - lzr;

    int nzr = ex_nz;
    int dr0, dr1, dr2, dr3;
    if (z3) nzr = j0 + 3; dr3 = nzr - (j0 + 3);
    if (z2) nzr = j0 + 2; dr2 = nzr - (j0 + 2);
    if (z1) nzr = j0 + 1; dr1 = nzr - (j0 + 1);
    if (z0) nzr = j0;     dr0 = nzr - j0;

    float d0 = fminf((float)min(dl0, dr0), BIGF);
    float d1 = fminf((float)min(dl1, dr1), BIGF);
    float d2 = fminf((float)min(dl2, dr2), BIGF);
    float d3 = fminf((float)min(dl3, dr3), BIGF);

    float4 o;
    o.x = d0 * d0; o.y = d1 * d1; o.z = d2 * d2; o.w = d3 * d3;
    ((float4*)(g2 + (size_t)wid * W))[lane] = o;
}

// ---------------------------------------------------------------------------
// Column pass: per (slice, 64-row quad, 16-col tile).
// Exact windowed min-plus: winning k must satisfy (i-k)^2 <= g2[i][j]
// (the k=i candidate), so restrict to the wave-uniform window. All candidate
// values are exact ints (<2^24) unless BIG-involved (then R caps at 255 ->
// full range), so min-over-window == reference min bitwise.
// Transposed LDS tile: one ds_read_b128 per 4 k-values.
// ---------------------------------------------------------------------------
__launch_bounds__(256)
__global__ void col_pass_kernel(const float* __restrict__ g2, float* __restrict__ dt,
                                unsigned* __restrict__ smax) {
    __shared__ float tileT[COLS][PADH];     // 16.6 KB, transposed (col-major k)
    int slice = blockIdx.z;
    int i0 = blockIdx.y * ROWQ;
    int j0 = blockIdx.x * COLS;
    const float* g2s = g2 + (size_t)slice * HW;

    // stage [256 k][16 cols] -> transposed LDS; pad k=256..259 with huge
    for (int e = threadIdx.x; e < H * COLS / 4; e += 256) {
        int k = e >> 2, q = e & 3;
        float4 v = *(const float4*)(g2s + (size_t)k * W + j0 + q * 4);
        tileT[q * 4 + 0][k] = v.x;
        tileT[q * 4 + 1][k] = v.y;
        tileT[q * 4 + 2][k] = v.z;
        tileT[q * 4 + 3][k] = v.w;
    }
    if (threadIdx.x < 64)
        tileT[threadIdx.x >> 2][H + (threadIdx.x & 3)] = 1.0e30f;
    __syncthreads();

    int jl = threadIdx.x & (COLS - 1);
    int ig = threadIdx.x >> 4;
    int ibase = i0 + ig * 4;            // 4 output rows per thread

    // per-thread window radius from the k=i candidates (exact upper bound)
    float4 gd = *(const float4*)&tileT[jl][ibase];
    float gmax = fmaxf(fmaxf(gd.x, gd.y), fmaxf(gd.z, gd.w));
    int R = (int)sqrtf(gmax) + 2;
    if (R > 255) R = 255;
    int lo = ibase - R, hi = ibase + 3 + R;
    #pragma unroll
    for (int off = 1; off < 64; off <<= 1) {
        lo = min(lo, __shfl_xor(lo, off));
        hi = max(hi, __shfl_xor(hi, off));
    }
    int kmin = (lo < 0 ? 0 : lo) & ~3;
    int kmax = hi > H - 1 ? H - 1 : hi;

    float m0 = 3.0e38f, m1 = 3.0e38f, m2 = 3.0e38f, m3 = 3.0e38f;
    float d0 = (float)(ibase - kmin);
    float d1 = d0 + 1.0f, d2 = d0 + 2.0f, d3 = d0 + 3.0f;

    const float* rowp = &tileT[jl][0];
    for (int k4 = kmin; k4 <= kmax; k4 += 4) {
        const float4 g = *(const float4*)(rowp + k4);
        {
            float gv = g.x;
            m0 = fminf(m0, fmaf(d0, d0, gv)); d0 -= 1.0f;
            m1 = fminf(m1, fmaf(d1, d1, gv)); d1 -= 1.0f;
            m2 = fminf(m2, fmaf(d2, d2, gv)); d2 -= 1.0f;
            m3 = fminf(m3, fmaf(d3, d3, gv)); d3 -= 1.0f;
        }
        {
            float gv = g.y;
            m0 = fminf(m0, fmaf(d0, d0, gv)); d0 -= 1.0f;
            m1 = fminf(m1, fmaf(d1, d1, gv)); d1 -= 1.0f;
            m2 = fminf(m2, fmaf(d2, d2, gv)); d2 -= 1.0f;
            m3 = fminf(m3, fmaf(d3, d3, gv)); d3 -= 1.0f;
        }
        {
            float gv = g.z;
            m0 = fminf(m0, fmaf(d0, d0, gv)); d0 -= 1.0f;
            m1 = fminf(m1, fmaf(d1, d1, gv)); d1 -= 1.0f;
            m2 = fminf(m2, fmaf(d2, d2, gv)); d2 -= 1.0f;
            m3 = fminf(m3, fmaf(d3, d3, gv)); d3 -= 1.0f;
        }
        {
            float gv = g.w;
            m0 = fminf(m0, fmaf(d0, d0, gv)); d0 -= 1.0f;
            m1 = fminf(m1, fmaf(d1, d1, gv)); d1 -= 1.0f;
            m2 = fminf(m2, fmaf(d2, d2, gv)); d2 -= 1.0f;
            m3 = fminf(m3, fmaf(d3, d3, gv)); d3 -= 1.0f;
        }
    }

    float* dts = dt + (size_t)slice * HW + (size_t)ibase * W + j0 + jl;
    float v0 = sqrtf(m0), v1 = sqrtf(m1), v2 = sqrtf(m2), v3 = sqrtf(m3);
    dts[0] = v0; dts[W] = v1; dts[2 * W] = v2; dts[3 * W] = v3;

    float lmax = fmaxf(fmaxf(v0, v1), fmaxf(v2, v3));
    #pragma unroll
    for (int off = 32; off; off >>= 1) lmax = fmaxf(lmax, __shfl_down(lmax, off));
    if ((threadIdx.x & 63) == 0) atomicMax(&smax[slice], __float_as_uint(lmax));
}

// In-place: out = (dt / max) * w[c]   (same op order as reference)
__global__ void norm_kernel(float* __restrict__ out, const unsigned* __restrict__ smax,
                            const float* __restrict__ w) {
    int idx = blockIdx.x * blockDim.x + threadIdx.x;   // float4 index
    if (idx >= TOTAL / 4) return;
    int slice = idx >> 14;
    int c = slice % C;
    float mx = __uint_as_float(smax[slice]);
    float den = mx > 0.0f ? mx : 1.0f;
    float wc = w[c];
    float4 v = ((float4*)out)[idx];
    v.x = (v.x / den) * wc;
    v.y = (v.y / den) * wc;
    v.z = (v.z / den) * wc;
    v.w = (v.w / den) * wc;
    ((float4*)out)[idx] = v;
}

extern "C" void kernel_launch(void* const* d_in, const int* in_sizes, int n_in,
                              void* d_out, int out_size, void* d_ws, size_t ws_size,
                              hipStream_t stream) {
    const float* in = (const float*)d_in[0];
    const float* w  = (const float*)d_in[1];
    float* out = (float*)d_out;
    float* g2 = (float*)d_ws;
    unsigned* smax = (unsigned*)((char*)d_ws + (size_t)TOTAL * sizeof(float));

    row_pass_kernel<<<ROWS * 64 / 256, 256, 0, stream>>>(in, g2, smax);
    col_pass_kernel<<<dim3(W / COLS, H / ROWQ, SLICES), 256, 0, stream>>>(g2, out, smax);
    norm_kernel<<<(TOTAL / 4 + 255) / 256, 256, 0, stream>>>(out, smax, w);
}

// Round 4
// 20.431 us; speedup vs baseline: 5.2654x; 2.5425x over previous
//
#include <hip/hip_runtime.h>

#define BIGF 1.0e6f

static constexpr int B = 4, C = 3, H = 256, W = 256;
static constexpr int SLICES = B * C;        // 12
static constexpr int ROWS = SLICES * H;     // 3072
static constexpr int HW = H * W;            // 65536
static constexpr int TOTAL = SLICES * HW;   // 786432
static constexpr int COLS = 16;             // columns per block in col pass
static constexpr int ROWQ = 64;             // output rows per block in col pass
static constexpr int PADH = H + 4;          // 260: 16B-aligned rows, ~2-way banks
static constexpr int BPS = 64;              // blocks per slice in col pass (16x4)

// ---------------------------------------------------------------------------
// Row pass: exact 1D distance along W, one WAVE per row (4 px/lane).
// d[j] = min(j - lastzero<=j, nextzero>=j - j, BIG)  ==  reference two-scan.
// ---------------------------------------------------------------------------
__global__ void row_pass_kernel(const float* __restrict__ in, float* __restrict__ g2) {
    int wid = (blockIdx.x * blockDim.x + threadIdx.x) >> 6;   // global wave = row
    int lane = threadIdx.x & 63;
    if (wid >= ROWS) return;

    const float4 v = ((const float4*)(in + (size_t)wid * W))[lane];
    int j0 = lane * 4;
    const int NEG = -(1 << 29), POS = (1 << 29);

    bool z0 = (v.x == 0.0f), z1 = (v.y == 0.0f), z2 = (v.z == 0.0f), z3 = (v.w == 0.0f);
    int lz = NEG;
    if (z0) lz = j0;
    if (z1) lz = j0 + 1;
    if (z2) lz = j0 + 2;
    if (z3) lz = j0 + 3;
    int nz = POS;
    if (z3) nz = j0 + 3;
    if (z2) nz = j0 + 2;
    if (z1) nz = j0 + 1;
    if (z0) nz = j0;

    int plz = lz;
    #pragma unroll
    for (int off = 1; off < 64; off <<= 1) {
        int o = __shfl_up(plz, off);
        if (lane >= off) plz = max(plz, o);
    }
    int ex_lz = __shfl_up(plz, 1);
    if (lane == 0) ex_lz = NEG;

    int pnz = nz;
    #pragma unroll
    for (int off = 1; off < 64; off <<= 1) {
        int o = __shfl_down(pnz, off);
        if (lane + off < 64) pnz = min(pnz, o);
    }
    int ex_nz = __shfl_down(pnz, 1);
    if (lane == 63) ex_nz = POS;

    int lzr = ex_lz;
    int dl0, dl1, dl2, dl3;
    if (z0) lzr = j0;     dl0 = j0 - lzr;
    if (z1) lzr = j0 + 1; dl1 = j0 + 1 - lzr;
    if (z2) lzr = j0 + 2; dl2 = j0 + 2 - lzr;
    if (z3) lzr = j0 + 3; dl3 = j0 + 3 - lzr;

    int nzr = ex_nz;
    int dr0, dr1, dr2, dr3;
    if (z3) nzr = j0 + 3; dr3 = nzr - (j0 + 3);
    if (z2) nzr = j0 + 2; dr2 = nzr - (j0 + 2);
    if (z1) nzr = j0 + 1; dr1 = nzr - (j0 + 1);
    if (z0) nzr = j0;     dr0 = nzr - j0;

    float d0 = fminf((float)min(dl0, dr0), BIGF);
    float d1 = fminf((float)min(dl1, dr1), BIGF);
    float d2 = fminf((float)min(dl2, dr2), BIGF);
    float d3 = fminf((float)min(dl3, dr3), BIGF);

    float4 o;
    o.x = d0 * d0; o.y = d1 * d1; o.z = d2 * d2; o.w = d3 * d3;
    ((float4*)(g2 + (size_t)wid * W))[lane] = o;
}

// ---------------------------------------------------------------------------
// Column pass: per (slice, 64-row quad, 16-col tile). Exact windowed min-plus
// (winning k satisfies (i-k)^2 <= g2[i][j], the k=i candidate). Per-BLOCK max
// written to a dedicated slot -> ZERO atomics (round-3 floor was same-line
// atomic serialization: 3072 atomicMax to one 48B line ~= 40 us).
// ---------------------------------------------------------------------------
__launch_bounds__(256)
__global__ void col_pass_kernel(const float* __restrict__ g2, float* __restrict__ dt,
                                float* __restrict__ bmax) {
    __shared__ float tileT[COLS][PADH];     // 16.6 KB, transposed (k contiguous)
    __shared__ float wred[4];
    int slice = blockIdx.z;
    int i0 = blockIdx.y * ROWQ;
    int j0 = blockIdx.x * COLS;
    const float* g2s = g2 + (size_t)slice * HW;

    for (int e = threadIdx.x; e < H * COLS / 4; e += 256) {
        int k = e >> 2, q = e & 3;
        float4 v = *(const float4*)(g2s + (size_t)k * W + j0 + q * 4);
        tileT[q * 4 + 0][k] = v.x;
        tileT[q * 4 + 1][k] = v.y;
        tileT[q * 4 + 2][k] = v.z;
        tileT[q * 4 + 3][k] = v.w;
    }
    if (threadIdx.x < 64)
        tileT[threadIdx.x >> 2][H + (threadIdx.x & 3)] = 1.0e30f;
    __syncthreads();

    int jl = threadIdx.x & (COLS - 1);
    int ig = threadIdx.x >> 4;
    int ibase = i0 + ig * 4;            // 4 output rows per thread

    // wave-uniform exact window from the k=i candidates
    float4 gd = *(const float4*)&tileT[jl][ibase];
    float gmax = fmaxf(fmaxf(gd.x, gd.y), fmaxf(gd.z, gd.w));
    int R = (int)sqrtf(gmax) + 2;
    if (R > 255) R = 255;
    int lo = ibase - R, hi = ibase + 3 + R;
    #pragma unroll
    for (int off = 1; off < 64; off <<= 1) {
        lo = min(lo, __shfl_xor(lo, off));
        hi = max(hi, __shfl_xor(hi, off));
    }
    int kmin = (lo < 0 ? 0 : lo) & ~3;
    int kmax = hi > H - 1 ? H - 1 : hi;

    float m0 = 3.0e38f, m1 = 3.0e38f, m2 = 3.0e38f, m3 = 3.0e38f;
    float d0 = (float)(ibase - kmin);
    float d1 = d0 + 1.0f, d2 = d0 + 2.0f, d3 = d0 + 3.0f;

    const float* rowp = &tileT[jl][0];
    for (int k4 = kmin; k4 <= kmax; k4 += 4) {
        const float4 g = *(const float4*)(rowp + k4);
        {
            float gv = g.x;
            m0 = fminf(m0, fmaf(d0, d0, gv)); d0 -= 1.0f;
            m1 = fminf(m1, fmaf(d1, d1, gv)); d1 -= 1.0f;
            m2 = fminf(m2, fmaf(d2, d2, gv)); d2 -= 1.0f;
            m3 = fminf(m3, fmaf(d3, d3, gv)); d3 -= 1.0f;
        }
        {
            float gv = g.y;
            m0 = fminf(m0, fmaf(d0, d0, gv)); d0 -= 1.0f;
            m1 = fminf(m1, fmaf(d1, d1, gv)); d1 -= 1.0f;
            m2 = fminf(m2, fmaf(d2, d2, gv)); d2 -= 1.0f;
            m3 = fminf(m3, fmaf(d3, d3, gv)); d3 -= 1.0f;
        }
        {
            float gv = g.z;
            m0 = fminf(m0, fmaf(d0, d0, gv)); d0 -= 1.0f;
            m1 = fminf(m1, fmaf(d1, d1, gv)); d1 -= 1.0f;
            m2 = fminf(m2, fmaf(d2, d2, gv)); d2 -= 1.0f;
            m3 = fminf(m3, fmaf(d3, d3, gv)); d3 -= 1.0f;
        }
        {
            float gv = g.w;
            m0 = fminf(m0, fmaf(d0, d0, gv)); d0 -= 1.0f;
            m1 = fminf(m1, fmaf(d1, d1, gv)); d1 -= 1.0f;
            m2 = fminf(m2, fmaf(d2, d2, gv)); d2 -= 1.0f;
            m3 = fminf(m3, fmaf(d3, d3, gv)); d3 -= 1.0f;
        }
    }

    float* dts = dt + (size_t)slice * HW + (size_t)ibase * W + j0 + jl;
    float v0 = sqrtf(m0), v1 = sqrtf(m1), v2 = sqrtf(m2), v3 = sqrtf(m3);
    dts[0] = v0; dts[W] = v1; dts[2 * W] = v2; dts[3 * W] = v3;

    // block-level max, ONE plain store per block (no atomics)
    float lmax = fmaxf(fmaxf(v0, v1), fmaxf(v2, v3));
    #pragma unroll
    for (int off = 32; off; off >>= 1) lmax = fmaxf(lmax, __shfl_down(lmax, off));
    if ((threadIdx.x & 63) == 0) wred[threadIdx.x >> 6] = lmax;
    __syncthreads();
    if (threadIdx.x == 0) {
        float bm = fmaxf(fmaxf(wred[0], wred[1]), fmaxf(wred[2], wred[3]));
        bmax[slice * BPS + blockIdx.y * (W / COLS) + blockIdx.x] = bm;
    }
}

// out = (dt / max) * w[c]; slice max rebuilt from the 64 per-block maxima
// via a 64-lane load + shfl reduction (exact, order-free).
__global__ void norm_kernel(float* __restrict__ out, const float* __restrict__ bmax,
                            const float* __restrict__ w) {
    int idx = blockIdx.x * blockDim.x + threadIdx.x;   // float4 index
    if (idx >= TOTAL / 4) return;
    int slice = idx >> 14;              // uniform within a block (256 idx/block)
    int c = slice % C;

    int lane = threadIdx.x & 63;
    float pm = bmax[slice * BPS + lane];
    #pragma unroll
    for (int off = 32; off; off >>= 1) pm = fmaxf(pm, __shfl_xor(pm, off));

    float den = pm > 0.0f ? pm : 1.0f;
    float wc = w[c];
    float4 v = ((float4*)out)[idx];
    v.x = (v.x / den) * wc;
    v.y = (v.y / den) * wc;
    v.z = (v.z / den) * wc;
    v.w = (v.w / den) * wc;
    ((float4*)out)[idx] = v;
}

extern "C" void kernel_launch(void* const* d_in, const int* in_sizes, int n_in,
                              void* d_out, int out_size, void* d_ws, size_t ws_size,
                              hipStream_t stream) {
    const float* in = (const float*)d_in[0];
    const float* w  = (const float*)d_in[1];
    float* out = (float*)d_out;
    float* g2 = (float*)d_ws;
    float* bmax = (float*)((char*)d_ws + (size_t)TOTAL * sizeof(float));

    row_pass_kernel<<<ROWS * 64 / 256, 256, 0, stream>>>(in, g2);
    col_pass_kernel<<<dim3(W / COLS, H / ROWQ, SLICES), 256, 0, stream>>>(g2, out, bmax);
    norm_kernel<<<(TOTAL / 4 + 255) / 256, 256, 0, stream>>>(out, bmax, w);
}